// Round 1
// 21666.039 us; speedup vs baseline: 1.6473x; 1.6473x over previous
//
#include <hip/hip_runtime.h>

typedef __bf16 bf16;
typedef __bf16 bf16x8 __attribute__((ext_vector_type(8)));
typedef __bf16 bf16x4 __attribute__((ext_vector_type(4)));
typedef float f32x4 __attribute__((ext_vector_type(4)));
typedef unsigned long long u64;

#define SCOPE_AGENT __HIP_MEMORY_SCOPE_AGENT

// B=32, T=256, H=1024, HY=256, E=64, L=2
// d_out = h_seq (32,256,1024) ++ h_last (32,1024) ++ c_last (32,1024), fp32
//
// Round N: two-layer software pipeline. One persistent seq dispatch with 256
// blocks (== CU count): blocks 0-127 run layer 0, blocks 128-255 run layer 1
// lagging one step. Layer-1 computes x@w_ih1 and the hyper x-part per step
// (was precomputed via gemm_pre over Y0). Cuts 512 serialized 63us steps to
// ~257 pipelined steps.

__device__ __forceinline__ float sigf(float x) { return 1.0f / (1.0f + __expf(-x)); }
__device__ __forceinline__ float tanhf_fast(float x) {
  float e = __expf(-2.0f * fabsf(x));
  float r = (1.0f - e) / (1.0f + e);
  return copysignf(r, x);
}
__device__ __forceinline__ f32x4 mfma16(bf16x8 a, bf16x8 b, f32x4 c) {
  return __builtin_amdgcn_mfma_f32_16x16x32_bf16(a, b, c, 0, 0, 0);
}
// Agent-scope (MALL-coherent) primitives: NO fences -> no buffer_wbl2/buffer_inv.
__device__ __forceinline__ u64 uld(const u64* p) { return __hip_atomic_load(p, __ATOMIC_RELAXED, SCOPE_AGENT); }
__device__ __forceinline__ void ust(u64* p, u64 v) { __hip_atomic_store(p, v, __ATOMIC_RELAXED, SCOPE_AGENT); }
__device__ __forceinline__ int ildi(const int* p) { return __hip_atomic_load(p, __ATOMIC_RELAXED, SCOPE_AGENT); }
__device__ __forceinline__ void isti(int* p, int v) { __hip_atomic_store(p, v, __ATOMIC_RELAXED, SCOPE_AGENT); }
__device__ __forceinline__ void fstf(float* p, float v) { __hip_atomic_store(p, v, __ATOMIC_RELAXED, SCOPE_AGENT); }

// ---------------- dtype detector ----------------
__global__ void detect_kernel(const void* probe, int* flag) {
  __shared__ int cnt;
  if (threadIdx.x == 0) cnt = 0;
  __syncthreads();
  const bf16* p = (const bf16*)probe;
  int local = 0;
  for (int j = threadIdx.x; j < 8192; j += 256) {
    float x = (float)p[j];
    bool wild = (x != x) || (fabsf(x) > 1e3f) || (x != 0.0f && fabsf(x) < 1e-30f);
    local += wild ? 1 : 0;
  }
  atomicAdd(&cnt, local);
  __syncthreads();
  if (threadIdx.x == 0) *flag = (cnt > 64) ? 1 : 0;
}

// ---------------- convert 15 tensors to canonical bf16 ----------------
struct CvtSrc { const void* s[15]; };
struct CvtDst { bf16* d[15]; };

__global__ __launch_bounds__(256) void convert_kernel(CvtSrc S, CvtDst D, const int* flag) {
  const int pre[16] = {0, 8388608, 16777216, 25165824, 29360128, 29884416, 29886464,
                       30017536, 30018048, 30149120, 30149632, 30280704, 30804992,
                       31329280, 31853568, 31861760};
  const int fp32 = *flag;
  const int nvec = 31861760 / 4;
  for (int v = blockIdx.x * 256 + threadIdx.x; v < nvec; v += gridDim.x * 256) {
    int e = v * 4;
    int seg = 0;
#pragma unroll
    for (int k = 1; k < 15; ++k) seg += (e >= pre[k]) ? 1 : 0;
    int off = e - pre[seg];
    bf16* d = D.d[seg] + off;
    if (fp32) {
      const float* s = (const float*)S.s[seg] + off;
      float4 x = *(const float4*)s;
      d[0] = (bf16)x.x; d[1] = (bf16)x.y; d[2] = (bf16)x.z; d[3] = (bf16)x.w;
    } else {
      const bf16* s = (const bf16*)S.s[seg] + off;
      d[0] = s[0]; d[1] = s[1]; d[2] = s[2]; d[3] = s[3];
    }
  }
}

// ---------------- init: zero publish buffers + flags (both layers) ----------------
// zbase covers: hpub0,hpub1 (2*65536B) hhpub0,hhpub1 (2*16384B) x0pub (131072B)
// flags (32768B) = 327680 B = 40960 u64. 160 blocks x 256 threads.
__global__ void init_kernel(u64* zbase) {
  int i = blockIdx.x * 256 + threadIdx.x;
  zbase[i] = 0ull;
}

// ---------------- precompute GEMM (layer 0 only now) ----------------
__global__ __launch_bounds__(256) void gemm_pre(
    const bf16* __restrict__ A, const bf16* __restrict__ w_ih_l,
    const bf16* __restrict__ hwih_l, bf16* __restrict__ Xp, float* __restrict__ Hxp) {
  constexpr int LDT = 72;
  __shared__ alignas(16) bf16 As[64 * LDT];
  __shared__ alignas(16) bf16 Bs[64 * LDT];
  const int bm = blockIdx.x & 127;
  const int bn = blockIdx.x >> 7;
  const int m0 = bm * 64, n0 = bn * 64;
  const int tid = threadIdx.x;
  const int lane = tid & 63, wid = tid >> 6;
  const int l15 = lane & 15, q = lane >> 4;
  const int srow = tid >> 2, sk = (tid & 3) * 16;
  const bf16* arow = A + (size_t)(m0 + srow) * 1024;
  const int n = n0 + srow;
  const bf16* brow = (n < 4096) ? (w_ih_l + (size_t)n * 1024)
                                : (hwih_l + (size_t)(n - 4096) * 2048);
  f32x4 acc[4] = {};
  for (int kb = 0; kb < 1024; kb += 64) {
    *(bf16x8*)(&As[srow * LDT + sk])     = *(const bf16x8*)(arow + kb + sk);
    *(bf16x8*)(&As[srow * LDT + sk + 8]) = *(const bf16x8*)(arow + kb + sk + 8);
    *(bf16x8*)(&Bs[srow * LDT + sk])     = *(const bf16x8*)(brow + kb + sk);
    *(bf16x8*)(&Bs[srow * LDT + sk + 8]) = *(const bf16x8*)(brow + kb + sk + 8);
    __syncthreads();
#pragma unroll
    for (int kk = 0; kk < 64; kk += 32) {
      bf16x8 av = *(const bf16x8*)(&As[(wid * 16 + l15) * LDT + kk + q * 8]);
#pragma unroll
      for (int j = 0; j < 4; ++j) {
        bf16x8 bv = *(const bf16x8*)(&Bs[(j * 16 + l15) * LDT + kk + q * 8]);
        acc[j] = mfma16(av, bv, acc[j]);
      }
    }
    __syncthreads();
  }
#pragma unroll
  for (int j = 0; j < 4; ++j) {
    const int gn = n0 + j * 16 + l15;
#pragma unroll
    for (int r = 0; r < 4; ++r) {
      const int gm = m0 + wid * 16 + q * 4 + r;
      float v = acc[j][r];
      if (gn < 4096) Xp[(size_t)gm * 4096 + gn] = (bf16)v;
      else           Hxp[(size_t)gm * 1024 + (gn - 4096)] = v;
    }
  }
}

struct SeqArgs {
  const bf16 *w_ih, *w_hh, *hwih, *hwhh, *hyb;
  const bf16 *w_zh, *b_zh, *w_zx, *b_zx, *w_zb;
  const bf16 *w_dh, *w_dx, *w_db, *b0;
  const bf16 *Xp; const float *Hxp;
  u64 *hpub, *hhpub, *x0pub; float *hgpub;
  float *outp;
  int *flags;
};

// ---------------- persistent pipelined kernel: both layers, 256 steps -------------
// 256 blocks x 256 thr. blk>>7 = layer; lblk = blk&127 = bq*16 + s16.
// Layer 1 runs one step behind layer 0, consuming x0pub[t&1] = h0(t).
// Flags: genp0@0, genp1@16, arrive0@64, arrive1@2112, hgfp0@4160, hgfp1@4416.
__global__ __launch_bounds__(256) void seq_kernel(SeqArgs a) {
  __shared__ char smem[60160] __attribute__((aligned(16)));
  // hyper-role arrays (dead before BC reuse; separated by __syncthreads)
  bf16 (*hstage)[520]  = (bf16(*)[520])smem;              // 32x520 bf16 = 33280
  bf16 (*hhstage)[264] = (bf16(*)[264])(smem + 33280);    // 32x264 bf16 = 16896
  // BC-role arrays
  bf16 (*hA4)[1032]   = (bf16(*)[1032])smem;              // 8256
  bf16 (*x0A4)[1032]  = (bf16(*)[1032])(smem + 8256);     // 8256 (layer 1 only)
  bf16 (*hh2A)[264]   = (bf16(*)[264])(smem + 16512);     // 2112
  float (*RhL)[256]   = (float(*)[256])(smem + 18624);    // 4096
  float (*XhL)[256]   = (float(*)[256])(smem + 22720);    // 4096 (layer 1 only)
  float (*hgs)[1024]  = (float(*)[1024])(smem + 26816);   // 16384
  float (*zsL)[768]   = (float(*)[768])(smem + 43200);    // 12288
  float (*presL)[256] = (float(*)[256])(smem + 55488);    // 4096
  bf16 (*hbuf)[64]    = (bf16(*)[64])(smem + 59584);      // 512

  const int tid = threadIdx.x;
  const int lane = tid & 63, wid = tid >> 6;
  const int l15 = lane & 15, q = lane >> 4;
  const int blk = blockIdx.x;
  const int layer = blk >> 7;
  const int lblk = blk & 127;
  const int bq = lblk >> 4, s16 = lblk & 15;
  const bool isHyper = ((s16 >> 1) == bq);
  const int hj = bq * 2 + (s16 & 1);

  u64*   hpub  = a.hpub  + layer * 8192;
  u64*   hhpub = a.hhpub + layer * 2048;
  float* hgpub = a.hgpub + layer * 32768;
  int* genp  = a.flags + layer * 16;
  int* ogenp = a.flags + (1 - layer) * 16;
  int* arrp  = a.flags + 64 + layer * 2048;
  int* hgfp  = a.flags + 4160 + layer * 256;

  const bf16* whh_l = a.w_hh + (size_t)layer * 4194304;
  const bf16* hybl  = a.hyb + layer * 1024;
  const bf16* bzh_l = a.b_zh + layer * 256;
  const bf16* bzx_l = a.b_zx + layer * 256;
  const bf16* b0_l  = a.b0 + (size_t)layer * 4096;
  const int cb = tid >> 6, chl = tid & 63;

  float c_reg = 0.0f;        // main c -- block-private
  float hc[4] = {0,0,0,0};   // hyper c -- replicated per block, deterministic

  // z B-row pointers (fixed over t)
  const bf16* zrow[12];
#pragma unroll
  for (int j = 0; j < 12; ++j) {
    int ng = wid * 12 + j, tau = ng >> 4;
    const bf16* base = (tau == 0) ? a.w_zh : (tau == 1) ? a.w_zx : a.w_zb;
    zrow[j] = base + ((size_t)layer * 256 + (ng & 15) * 16 + l15) * 256;
  }
  const bf16* rrow[4];
  const bf16* xrow[4];
#pragma unroll
  for (int nt = 0; nt < 4; ++nt) {
    rrow[nt] = whh_l + (size_t)(wid * 1024 + s16 * 64 + nt * 16 + l15) * 1024;
    xrow[nt] = a.w_ih + (size_t)layer * 4194304
             + (size_t)(wid * 1024 + s16 * 64 + nt * 16 + l15) * 1024;
  }
  const size_t wdo = ((size_t)(layer * 4 + wid) * 1024 + s16 * 64 + lane) * 64;
  const bf16 *pdh = a.w_dh + wdo, *pdx = a.w_dx + wdo, *pdb = a.w_db + wdo;

  for (int t = 0; t < 256; ++t) {
    u64* x0slot = a.x0pub + (size_t)(t & 1) * 8192;
    // ---- start-of-step waits ----
    if (t > 0 && tid == 0) {
      while (ildi(genp) < t) __builtin_amdgcn_s_sleep(2);
    }
    if (tid == 64) {
      // layer 0: throttle so x0pub[t&1] (consumed in layer-1 step t-2) is free.
      // layer 1: wait for layer-0 step t complete (x0 = h0(t) available).
      const int need = layer ? (t + 1) : (t - 1);
      while (ildi(ogenp) < need) __builtin_amdgcn_s_sleep(2);
    }
    __atomic_signal_fence(__ATOMIC_SEQ_CST);
    __syncthreads();

    // ---- hyper role: hg[32][n-slice 64] = (x,)h@hWih^T + hh@hWhh^T ----
    if (isHyper) {
      for (int i = tid; i < 2048; i += 256) {
        int b = i >> 6, u = i & 63;
        *(u64*)&hhstage[b][u * 4] = uld(hhpub + i);
      }
      const bf16* bihrow = a.hwih + (size_t)layer * 2097152
                         + (size_t)(hj * 64 + wid * 16 + l15) * 2048;
      f32x4 cA = {}, cB = {};
      // layer 0: phases 2,3 (h halves, weight cols 1024/1536; x-part precomputed in Hxp)
      // layer 1: phases 0,1 (x halves from x0pub, cols 0/512) then 2,3 (h halves)
      for (int ph = layer ? 0 : 2; ph < 4; ++ph) {
        const u64* src = ((ph < 2) ? (const u64*)x0slot : (const u64*)hpub)
                       + ((ph & 1) << 7);
        for (int i = tid; i < 4096; i += 256) {
          int b = i >> 7, u = i & 127;
          *(u64*)&hstage[b][u * 4] = uld(src + ((size_t)b << 8) + u);
        }
        __syncthreads();
        const bf16* bw = bihrow + ph * 512;
        for (int kk = 0; kk < 512; kk += 32) {
          int ko = kk + q * 8;
          bf16x8 bv = *(const bf16x8*)(bw + ko);
          bf16x8 a0 = *(const bf16x8*)&hstage[l15][ko];
          bf16x8 a1 = *(const bf16x8*)&hstage[16 + l15][ko];
          cA = mfma16(a0, bv, cA); cB = mfma16(a1, bv, cB);
        }
        __syncthreads();
      }
      const bf16* bhh = a.hwhh + (size_t)layer * 262144
                      + (size_t)(hj * 64 + wid * 16 + l15) * 256;
      for (int kk = 0; kk < 256; kk += 32) {
        int ko = kk + q * 8;
        bf16x8 bv = *(const bf16x8*)(bhh + ko);
        bf16x8 a0 = *(const bf16x8*)&hhstage[l15][ko];
        bf16x8 a1 = *(const bf16x8*)&hhstage[16 + l15][ko];
        cA = mfma16(a0, bv, cA); cB = mfma16(a1, bv, cB);
      }
      const int n = hj * 64 + wid * 16 + l15;
#pragma unroll
      for (int r = 0; r < 4; ++r) {
        fstf(hgpub + (q * 4 + r) * 1024 + n, cA[r]);
        fstf(hgpub + (16 + q * 4 + r) * 1024 + n, cB[r]);
      }
      __atomic_signal_fence(__ATOMIC_SEQ_CST);
      __builtin_amdgcn_s_waitcnt(0);
      __syncthreads();
      if (tid == 0) isti(hgfp + hj * 16, t + 1);
    }
    __syncthreads();   // hyper smem dead; safe to reuse for BC arrays

    // ---- BC: own-Rh (M=4): Rh[4b][256n] = h_own @ w_hh_slice^T (+Xh for layer 1) ----
    for (int i = tid; i < 1024; i += 256) {
      int b = i >> 8, u = i & 255;
      *(u64*)&hA4[b][u * 4] = uld(hpub + ((size_t)(bq * 4 + b) << 8) + u);
    }
    if (layer) {
      for (int i = tid; i < 1024; i += 256) {
        int b = i >> 8, u = i & 255;
        *(u64*)&x0A4[b][u * 4] = uld((const u64*)x0slot + ((size_t)(bq * 4 + b) << 8) + u);
      }
    }
    __syncthreads();
    {
      f32x4 racc[4] = {};
      f32x4 xacc[4] = {};
      for (int kk = 0; kk < 1024; kk += 32) {
        const int ko = kk + q * 8;
        bf16x8 av = *(const bf16x8*)&hA4[l15 & 3][ko];
#pragma unroll
        for (int nt = 0; nt < 4; ++nt) {
          bf16x8 bv = *(const bf16x8*)(rrow[nt] + ko);
          racc[nt] = mfma16(av, bv, racc[nt]);
        }
        if (layer) {
          bf16x8 axv = *(const bf16x8*)&x0A4[l15 & 3][ko];
#pragma unroll
          for (int nt = 0; nt < 4; ++nt) {
            bf16x8 bv = *(const bf16x8*)(xrow[nt] + ko);
            xacc[nt] = mfma16(axv, bv, xacc[nt]);
          }
        }
      }
      if (lane < 16) {
#pragma unroll
        for (int nt = 0; nt < 4; ++nt)
#pragma unroll
          for (int r = 0; r < 4; ++r) {
            RhL[r][wid * 64 + nt * 16 + lane] = racc[nt][r];
            if (layer) XhL[r][wid * 64 + nt * 16 + lane] = xacc[nt][r];
          }
      }
    }
    // ---- wait for hg, stage own 4 batches ----
    if (tid < 16) { while (ildi(hgfp + tid * 16) < t + 1) __builtin_amdgcn_s_sleep(1); }
    __atomic_signal_fence(__ATOMIC_SEQ_CST);
    __syncthreads();
    {
      const u64* hg64 = (const u64*)hgpub;
      for (int i = tid; i < 2048; i += 256) {
        int b = i >> 9, u = i & 511;
        *(u64*)&hgs[b][u * 2] = uld(hg64 + ((size_t)(bq * 4 + b) << 9) + u);
      }
    }
    __syncthreads();
    // ---- hyper cell (replicated per block, deterministic) + hh2 ----
    {
      const float* hgr = hgs[cb];
      const float* hxr = a.Hxp + ((size_t)(bq * 4 + cb) * 256 + t) * 1024;
      const int d0 = chl * 4;
      float hh2v[4];
#pragma unroll
      for (int dd = 0; dd < 4; ++dd) {
        int d = d0 + dd;
        float hi  = hgr[d]       + (float)hybl[d];
        float hf  = hgr[256 + d] + (float)hybl[256 + d];
        float hgv = hgr[512 + d] + (float)hybl[512 + d];
        float ho  = hgr[768 + d] + (float)hybl[768 + d];
        if (layer == 0) {   // layer 1's x-part is already inside hg
          hi += hxr[d]; hf += hxr[256 + d]; hgv += hxr[512 + d]; ho += hxr[768 + d];
        }
        hc[dd] = sigf(hf) * hc[dd] + sigf(hi) * tanhf_fast(hgv);
        float v = sigf(ho) * tanhf_fast(hc[dd]);
        hh2v[dd] = v;
        hh2A[cb][d] = (bf16)v;
      }
      if (s16 == 0) {
        union { bf16 h[4]; u64 v; } pk;
#pragma unroll
        for (int dd = 0; dd < 4; ++dd) pk.h[dd] = (bf16)hh2v[dd];
        ust(hhpub + ((size_t)(bq * 4 + cb) << 6) + chl, pk.v);
      }
    }
    __syncthreads();
    // ---- z = hh2 @ wz^T (+bias), M=4 MFMA over 3x256 outputs ----
    {
      f32x4 zacc[12] = {};
      for (int kk = 0; kk < 256; kk += 32) {
        const int ko = kk + q * 8;
        bf16x8 av = *(const bf16x8*)&hh2A[l15 & 3][ko];
#pragma unroll
        for (int j = 0; j < 12; ++j) {
          bf16x8 bv = *(const bf16x8*)(zrow[j] + ko);
          zacc[j] = mfma16(av, bv, zacc[j]);
        }
      }
      if (lane < 16) {
#pragma unroll
        for (int j = 0; j < 12; ++j) {
          int ng = wid * 12 + j, tau = ng >> 4, col = (ng & 15) * 16 + lane;
          float bias = (tau == 0) ? (float)bzh_l[col] : (tau == 1) ? (float)bzx_l[col] : 0.0f;
#pragma unroll
          for (int r = 0; r < 4; ++r) zsL[r][tau * 256 + col] = zacc[j][r] + bias;
        }
      }
    }
    __syncthreads();
    // ---- d-projections + pre ----
    {
      float dH[4] = {}, dX[4] = {}, dB[4] = {};
      for (int e0 = 0; e0 < 64; e0 += 4) {
        bf16x4 wh = *(const bf16x4*)(pdh + e0);
        bf16x4 wx = *(const bf16x4*)(pdx + e0);
        bf16x4 wb = *(const bf16x4*)(pdb + e0);
        f32x4 zh_[4], zx_[4], zb_[4];
#pragma unroll
        for (int b = 0; b < 4; ++b) {
          zh_[b] = *(const f32x4*)&zsL[b][wid * 64 + e0];
          zx_[b] = *(const f32x4*)&zsL[b][256 + wid * 64 + e0];
          zb_[b] = *(const f32x4*)&zsL[b][512 + wid * 64 + e0];
        }
#pragma unroll
        for (int jj = 0; jj < 4; ++jj) {
          float whf = (float)wh[jj], wxf = (float)wx[jj], wbf = (float)wb[jj];
#pragma unroll
          for (int b = 0; b < 4; ++b) {
            dH[b] += zh_[b][jj] * whf;
            dX[b] += zx_[b][jj] * wxf;
            dB[b] += zb_[b][jj] * wbf;
          }
        }
      }
#pragma unroll
      for (int b = 0; b < 4; ++b) {
        float rh = RhL[b][wid * 64 + lane];
        float xp = layer ? XhL[b][wid * 64 + lane]
                         : (float)a.Xp[((size_t)(bq * 4 + b) * 256 + t) * 4096
                                       + wid * 1024 + s16 * 64 + lane];
        float b0v = (float)b0_l[wid * 1024 + s16 * 64 + lane];
        presL[b][wid * 64 + lane] = dH[b] * rh + dX[b] * xp + dB[b] + b0v;
      }
    }
    __syncthreads();
    // ---- main cell + outputs ----
    {
      float iv = presL[cb][chl];
      float fv = presL[cb][64 + chl];
      float gv = presL[cb][128 + chl];
      float ov = presL[cb][192 + chl];
      c_reg = sigf(fv) * c_reg + sigf(iv) * tanhf_fast(gv);
      float hn = sigf(ov) * tanhf_fast(c_reg);
      hbuf[cb][chl] = (bf16)hn;
      if (layer) {
        const size_t oo = ((size_t)(bq * 4 + cb) * 256 + t) * 1024 + s16 * 64 + chl;
        a.outp[oo] = hn;
        if (t == 255) {
          a.outp[8388608 + (bq * 4 + cb) * 1024 + s16 * 64 + chl] = hn;
          a.outp[8421376 + (bq * 4 + cb) * 1024 + s16 * 64 + chl] = c_reg;
        }
      }
    }
    __syncthreads();
    // ---- publish own h slice (layer 0 also -> x0pub[t&1]), then layer barrier ----
    if (tid < 64) {
      int b = tid >> 4, u = tid & 15;
      u64 pk = *(const u64*)&hbuf[b][u * 4];
      ust(hpub + ((size_t)(bq * 4 + b) << 8) + s16 * 16 + u, pk);
      if (layer == 0)
        ust(x0slot + ((size_t)(bq * 4 + b) << 8) + s16 * 16 + u, pk);
    }
    __atomic_signal_fence(__ATOMIC_SEQ_CST);
    __builtin_amdgcn_s_waitcnt(0);
    __syncthreads();
    if (tid == 0) isti(arrp + lblk * 16, t + 1);
    if (lblk == 0 && wid == 0) {   // per-layer master sweep: 64 lanes x 2 slots
      const int t1 = t + 1;
      for (;;) {
        int v0 = ildi(arrp + lane * 32);
        int v1 = ildi(arrp + lane * 32 + 16);
        if (__all((v0 >= t1) && (v1 >= t1))) break;
        __builtin_amdgcn_s_sleep(2);
      }
      __atomic_signal_fence(__ATOMIC_SEQ_CST);
      if (lane == 0) isti(genp, t1);
    }
  }
}

extern "C" void kernel_launch(void* const* d_in, const int* in_sizes, int n_in,
                              void* d_out, int out_size, void* d_ws, size_t ws_size,
                              hipStream_t stream) {
  float* outp = (float*)d_out;
  char* ws = (char*)d_ws;
  bf16*  Xp     = (bf16*) (ws);                      // 67,108,864 (layer 0 only)
  float* Hxp    = (float*)(ws + 67108864ull);        // 33,554,432 (layer 0 only)
  char*  pubb   = ws + 100663296ull;                 // publish region (former Y0 slot)
  u64*   hpub   = (u64*)  (pubb + 0);                // 2 x 65,536
  u64*   hhpub  = (u64*)  (pubb + 131072);           // 2 x 16,384
  u64*   x0pub  = (u64*)  (pubb + 163840);           // 2 x 65,536 (parity dbuf)
  int*   flags  = (int*)  (pubb + 294912);           //     32,768
  float* hgpub  = (float*)(pubb + 327680);           // 2 x 131,072
  bf16* c_input = (bf16*)(ws + 117669888ull);        // 16,777,216
  bf16* c_w_ih  = (bf16*)(ws + 134447104ull);        // 16,777,216
  bf16* c_w_hh  = (bf16*)(ws + 151224320ull);        // 16,777,216
  bf16* c_hwih  = (bf16*)(ws + 168001536ull);        //  8,388,608
  bf16* c_hwhh  = (bf16*)(ws + 176390144ull);        //  1,048,576
  bf16* c_hyb   = (bf16*)(ws + 177438720ull);        //      4,096
  bf16* c_wzh   = (bf16*)(ws + 177442816ull);        //    262,144
  bf16* c_bzh   = (bf16*)(ws + 177704960ull);        //      1,024
  bf16* c_wzx   = (bf16*)(ws + 177705984ull);        //    262,144
  bf16* c_bzx   = (bf16*)(ws + 177968128ull);        //      1,024
  bf16* c_wzb   = (bf16*)(ws + 177969152ull);        //    262,144
  bf16* c_wdh   = (bf16*)(ws + 178231296ull);        //  1,048,576
  bf16* c_wdx   = (bf16*)(ws + 179279872ull);        //  1,048,576
  bf16* c_wdb   = (bf16*)(ws + 180328448ull);        //  1,048,576
  bf16* c_b0    = (bf16*)(ws + 181377024ull);        //     16,384
  int*  dflag   = (int*) (ws + 181393408ull);        //          4

  hipLaunchKernelGGL(detect_kernel, dim3(1), dim3(256), 0, stream, d_in[2], dflag);
  CvtSrc S; CvtDst D;
  for (int i = 0; i < 15; ++i) S.s[i] = d_in[i];
  D.d[0] = c_input; D.d[1] = c_w_ih; D.d[2] = c_w_hh; D.d[3] = c_hwih; D.d[4] = c_hwhh;
  D.d[5] = c_hyb;   D.d[6] = c_wzh;  D.d[7] = c_bzh;  D.d[8] = c_wzx;  D.d[9] = c_bzx;
  D.d[10] = c_wzb;  D.d[11] = c_wdh; D.d[12] = c_wdx; D.d[13] = c_wdb; D.d[14] = c_b0;
  hipLaunchKernelGGL(convert_kernel, dim3(2048), dim3(256), 0, stream, S, D, dflag);

  // zero pubs + flags for both layers (327,680 B = 40,960 u64)
  hipLaunchKernelGGL(init_kernel, dim3(160), dim3(256), 0, stream, (u64*)pubb);
  // layer-0 precompute only (layer 1's x-GEMMs are fused into the pipeline)
  hipLaunchKernelGGL(gemm_pre, dim3(10240), dim3(256), 0, stream,
                     c_input, c_w_ih, c_hwih, Xp, Hxp);

  SeqArgs sa;
  sa.w_ih = c_w_ih; sa.w_hh = c_w_hh; sa.hwih = c_hwih; sa.hwhh = c_hwhh; sa.hyb = c_hyb;
  sa.w_zh = c_wzh; sa.b_zh = c_bzh; sa.w_zx = c_wzx; sa.b_zx = c_bzx; sa.w_zb = c_wzb;
  sa.w_dh = c_wdh; sa.w_dx = c_wdx; sa.w_db = c_wdb; sa.b0 = c_b0;
  sa.Xp = Xp; sa.Hxp = Hxp;
  sa.hpub = hpub; sa.hhpub = hhpub; sa.x0pub = x0pub; sa.hgpub = hgpub;
  sa.outp = outp;
  sa.flags = flags;
  hipLaunchKernelGGL(seq_kernel, dim3(256), dim3(256), 0, stream, sa);
}